// Round 8
// baseline (344.035 us; speedup 1.0000x reference)
//
#include <hip/hip_runtime.h>
#include <math.h>

#define B 8
#define N 512
#define D 128
#define H 4
#define TOK (B*N)   // 4096

typedef __attribute__((ext_vector_type(8))) short bfrag;   // 8 bf16 (4 VGPRs)
typedef __attribute__((ext_vector_type(4))) float facc;    // 4 fp32 acc
typedef unsigned short u16;
typedef unsigned int u32;
typedef unsigned long long u64;

__device__ __forceinline__ float lrelu(float x){ return x > 0.f ? x : 0.01f*x; }
__device__ __forceinline__ u16 f2bf(float f){
  u32 u = __float_as_uint(f);
  u += 0x7fffu + ((u >> 16) & 1u);     // RTNE
  return (u16)(u >> 16);
}
__device__ __forceinline__ u32 pk2(float a, float b){
  return (u32)f2bf(a) | ((u32)f2bf(b) << 16);
}

// Barrier WITHOUT the compiler's vmcnt(0) drain: LDS writes are made visible
// (lgkmcnt(0)), but global->register prefetch loads stay in flight across the
// barrier (hipcc's __syncthreads() would drain them - the round-7 null).
__device__ __forceinline__ void bar_nd(){
  __builtin_amdgcn_sched_barrier(0);
  asm volatile("s_waitcnt lgkmcnt(0)" ::: "memory");
  __builtin_amdgcn_s_barrier();
  __builtin_amdgcn_sched_barrier(0);
}

// LDS row strides (u16): all give bank skew 4/row, 16B-aligned rows
#define LS 72        // B tiles / staged A tiles
#define ASF 264      // fel A tiles (K up to 256)
#define ASW 136      // wh-phase A tiles (K=128)

// ---------------- prep: fully parallel, 1 job per block -----------------------
__global__ void prep_kernel(const int* __restrict__ adj,
    u32* __restrict__ mbits, u32* __restrict__ mtbits,
    float* __restrict__ colsumF, float* __restrict__ colsumT,
    const float* s0, const float* s1_, const float* s2_, const float* s3,
    const float* s4, const float* s5, const float* s6, const float* s7,
    const float* s8,
    u16* d0, u16* d1, u16* d2, u16* d3, u16* d4, u16* d5, u16* d6, u16* d7, u16* d8)
{
  __shared__ int smem[64*65];
  const int tid = threadIdx.x;
  if (blockIdx.x < 512){
    const int tb = blockIdx.x;
    const int b = tb >> 6, i0 = ((tb >> 3) & 7)*64, j0 = (tb & 7)*64;
    #pragma unroll
    for (int i = 0; i < 4; ++i){
      const int r = i*16 + (tid >> 4);
      const int c = (tid & 15)*4;
      int4 v = *(const int4*)&adj[((size_t)b*N + i0 + r)*N + j0 + c];
      smem[r*65 + c]     = v.x; smem[r*65 + c + 1] = v.y;
      smem[r*65 + c + 2] = v.z; smem[r*65 + c + 3] = v.w;
    }
    __syncthreads();
    const int wv = tid >> 6, lane = tid & 63;
    #pragma unroll
    for (int q = 0; q < 16; ++q){
      const int r = wv*16 + q;
      u64 bf_ = __ballot(smem[r*65 + lane] > 0);
      if (lane == 0)
        *(u64*)&mbits[((size_t)b*N + i0 + r)*16 + (j0 >> 5)] = bf_;
      u64 bt_ = __ballot(smem[lane*65 + r] > 0);
      if (lane == 0)
        *(u64*)&mtbits[((size_t)b*N + j0 + r)*16 + (i0 >> 5)] = bt_;
    }
  } else if (blockIdx.x < 1460){
    float* ftile = (float*)smem;        // [32][33]
    const int tx = tid & 31, ty = tid >> 5;
    const float* srcs[9] = {s0,s1_,s2_,s3,s4,s5,s6,s7,s8};
    u16* dsts[9] = {d0,d1,d2,d3,d4,d5,d6,d7,d8};
    const int Ks[9] = {32,128,128,256,128,256,128,128,512};
    const int Ns[9] = {128,128,256,128,256,128,128,128,128};
    const int zs[9] = {1,1,1,1,1,1,24,2,6};
    const int job = (int)blockIdx.x - 512;      // [0,948)
    int m = 0, base = 0;
    for (; m < 9; ++m){
      int cnt = (Ks[m]>>5)*(Ns[m]>>5)*zs[m];
      if (job < base + cnt) break;
      base += cnt;
    }
    const int rem = job - base;
    const int tn = Ns[m] >> 5;
    const int per = (Ks[m] >> 5)*tn;
    const int z = rem / per, t = rem % per;
    const int k0 = (t / tn)*32, n0 = (t % tn)*32;
    const float* src = srcs[m] + (size_t)z*Ks[m]*Ns[m];
    u16* dst = dsts[m] + (size_t)z*Ks[m]*Ns[m];
    for (int r = ty; r < 32; r += 8)
      ftile[r*33 + tx] = src[(size_t)(k0+r)*Ns[m] + n0 + tx];
    __syncthreads();
    for (int r = ty; r < 32; r += 8)
      dst[(size_t)(n0+r)*Ks[m] + k0 + tx] = f2bf(ftile[tx*33 + r]);
  } else {
    float4 z = {0.f,0.f,0.f,0.f};
    *(float4*)&colsumF[tid*4] = z;
    *(float4*)&colsumT[tid*4] = z;
  }
}

// ---- staging helpers ---------------------------------------------------------
struct BPre { uint4 a,b,c,d; };
__device__ __forceinline__ BPre preB64(const u16* __restrict__ BTn, int ldb, int k0, int tid){
  const int n = tid >> 1, part = tid & 1;
  const u16* wp = BTn + (size_t)n*ldb + k0 + part*32;
  BPre r;
  r.a = *(const uint4*)wp;      r.b = *(const uint4*)(wp+8);
  r.c = *(const uint4*)(wp+16); r.d = *(const uint4*)(wp+24);
  return r;
}
__device__ __forceinline__ void landB64(const BPre& p, u16* Bs, int tid){
  const int n = tid >> 1, part = tid & 1;
  u16* bp = &Bs[n*LS + part*32];
  *(uint4*)bp = p.a; *(uint4*)(bp+8) = p.b; *(uint4*)(bp+16) = p.c; *(uint4*)(bp+24) = p.d;
}
__device__ __forceinline__ void stageB32(const u16* __restrict__ BTn, int ldb,
                                         int k0, u16* Bs, int tid){
  const int n = tid >> 1, part = tid & 1;
  const u16* wp = BTn + (size_t)n*ldb + k0 + part*16;
  uint4 w0 = *(const uint4*)wp, w1 = *(const uint4*)(wp+8);
  *(uint4*)&Bs[n*LS + part*16]     = w0;
  *(uint4*)&Bs[n*LS + part*16 + 8] = w1;
}
// 64-row (group-half) B staging: 256 group-threads, 16 u16 each
struct BPre2 { uint4 a,b; };
__device__ __forceinline__ BPre2 preBh(const u16* __restrict__ BTn, int ldb, int k0,
                                       int gtid, int rowoff){
  const u16* wp = BTn + (size_t)(rowoff + (gtid >> 2))*ldb + k0 + (gtid & 3)*16;
  BPre2 r; r.a = *(const uint4*)wp; r.b = *(const uint4*)(wp+8);
  return r;
}
__device__ __forceinline__ void landBh(const BPre2& p, u16* Bs, int gtid){
  u16* bp = &Bs[(gtid >> 2)*LS + (gtid & 3)*16];
  *(uint4*)bp = p.a; *(uint4*)(bp+8) = p.b;
}

// ---- MFMA cores --------------------------------------------------------------
// 4-wave 32x128 mapping (stride-parameterized A)
__device__ __forceinline__ void mfma64s(const u16* As, int sA, const u16* Bs,
                                        facc acc[4], int r0, int c0, int quad, int l15){
  #pragma unroll
  for (int kk = 0; kk < 2; ++kk){
    bfrag af = *(const bfrag*)&As[(r0 + l15)*sA + kk*32 + quad*8];
    #pragma unroll
    for (int g = 0; g < 4; ++g){
      bfrag bf = *(const bfrag*)&Bs[(c0 + g*16 + l15)*LS + kk*32 + quad*8];
      acc[g] = __builtin_amdgcn_mfma_f32_16x16x32_bf16(af, bf, acc[g], 0,0,0);
    }
  }
}
__device__ __forceinline__ void mfma32s(const u16* As, int sA, const u16* Bs,
                                        facc acc[4], int r0, int c0, int quad, int l15){
  bfrag af = *(const bfrag*)&As[(r0 + l15)*sA + quad*8];
  #pragma unroll
  for (int g = 0; g < 4; ++g){
    bfrag bf = *(const bfrag*)&Bs[(c0 + g*16 + l15)*LS + quad*8];
    acc[g] = __builtin_amdgcn_mfma_f32_16x16x32_bf16(af, bf, acc[g], 0,0,0);
  }
}
// wave = 32 rows x 16 cols (col-split groups in pv32/reshwh)
__device__ __forceinline__ void mfma64h(const u16* As, const u16* Bs,
                                        facc acc[2], int c0, int quad, int l15){
  #pragma unroll
  for (int kk = 0; kk < 2; ++kk){
    bfrag af0 = *(const bfrag*)&As[(l15)*LS      + kk*32 + quad*8];
    bfrag af1 = *(const bfrag*)&As[(16 + l15)*LS + kk*32 + quad*8];
    bfrag bf  = *(const bfrag*)&Bs[(c0 + l15)*LS + kk*32 + quad*8];
    acc[0] = __builtin_amdgcn_mfma_f32_16x16x32_bf16(af0, bf, acc[0], 0,0,0);
    acc[1] = __builtin_amdgcn_mfma_f32_16x16x32_bf16(af1, bf, acc[1], 0,0,0);
  }
}
// wave = 32 rows x 32 cols (pvout)
__device__ __forceinline__ void mfma64w(const u16* As, const u16* Bs,
                                        facc acc[2][2], int c0,
                                        int quad, int l15){
  #pragma unroll
  for (int kk = 0; kk < 2; ++kk){
    bfrag af0 = *(const bfrag*)&As[(l15)*LS      + kk*32 + quad*8];
    bfrag af1 = *(const bfrag*)&As[(16 + l15)*LS + kk*32 + quad*8];
    #pragma unroll
    for (int f = 0; f < 2; ++f){
      bfrag bf = *(const bfrag*)&Bs[(c0 + f*16 + l15)*LS + kk*32 + quad*8];
      acc[0][f] = __builtin_amdgcn_mfma_f32_16x16x32_bf16(af0, bf, acc[0][f], 0,0,0);
      acc[1][f] = __builtin_amdgcn_mfma_f32_16x16x32_bf16(af1, bf, acc[1][f], 0,0,0);
    }
  }
}

// ---- single-buffer A-in-LDS GEMM over T 64-wide K tiles (fel) ----------------
// nodrain barriers: next-tile reg prefetch stays in flight across them.
template<int T>
__device__ __forceinline__ void gemmAs(const u16* Aw, int sA,
    const u16* __restrict__ BT, int ldb, u16* Bs,
    facc acc[4], int tid, int r0, int c0, int quad, int l15){
  BPre p = preB64(BT, ldb, 0, tid);
  #pragma unroll
  for (int t = 0; t < T; ++t){
    bar_nd();                              // Bs writable; A writes visible below
    landB64(p, Bs, tid);
    if (t + 1 < T) p = preB64(BT, ldb, (t+1)*64, tid);
    bar_nd();
    mfma64s(Aw + t*64, sA, Bs, acc, r0, c0, quad, l15);
  }
}

// ---- WH phase (single-buffer, 256-thread version: fel / pvout) ---------------
template<int NH>
__device__ __forceinline__ void wh_phaseS(const u16* Aw, int sA, u16* Bs,
    const u16* __restrict__ WT, const float* __restrict__ aatt,
    int t0, u16* __restrict__ WhT, float* __restrict__ s1, float* __restrict__ s2,
    float (*r1s4)[2][32], float (*r2s4)[2][32], int tid)
{
  const int wave = tid >> 6, lane = tid & 63, quad = lane >> 4, l15 = lane & 15;
  const int r0 = (wave & 1)*16, c0 = (wave >> 1)*64;
  const int b = t0 >> 9, j0 = t0 & (N-1);
  BPre p = preB64(WT, D, 0, tid);
  facc acc[4];
  #pragma unroll
  for (int t = 0; t < 2*NH; ++t){
    if ((t & 1) == 0){
      #pragma unroll
      for (int g = 0; g < 4; ++g) acc[g] = (facc){0.f,0.f,0.f,0.f};
    }
    bar_nd();                              // Bs writable; Aw visible
    landB64(p, Bs, tid);
    if (t + 1 < 2*NH) p = preB64(WT + (size_t)((t+1)>>1)*D*D, D, ((t+1)&1)*64, tid);
    bar_nd();
    mfma64s(Aw + (t&1)*64, sA, Bs, acc, r0, c0, quad, l15);
    if (t & 1){
      const int h = t >> 1;
      const float* ah = aatt + (size_t)h*2*D;
      const size_t obase = (size_t)(h*8 + b)*128;
      float p1[4] = {0,0,0,0}, p2[4] = {0,0,0,0};
      #pragma unroll
      for (int g = 0; g < 4; ++g){
        const int c = c0 + g*16 + l15;
        const float a1v = ah[c], a2v = ah[D + c];
        ushort4 wv;
        wv.x = f2bf(acc[g][0]); wv.y = f2bf(acc[g][1]);
        wv.z = f2bf(acc[g][2]); wv.w = f2bf(acc[g][3]);
        *(ushort4*)&WhT[(obase + c)*N + j0 + r0 + quad*4] = wv;
        #pragma unroll
        for (int q = 0; q < 4; ++q){
          p1[q] = fmaf(acc[g][q], a1v, p1[q]);
          p2[q] = fmaf(acc[g][q], a2v, p2[q]);
        }
      }
      #pragma unroll
      for (int m = 1; m < 16; m <<= 1){
        #pragma unroll
        for (int q = 0; q < 4; ++q){ p1[q] += __shfl_xor(p1[q], m, 64); p2[q] += __shfl_xor(p2[q], m, 64); }
      }
      if (l15 == 0){
        #pragma unroll
        for (int q = 0; q < 4; ++q){
          r1s4[h][wave>>1][r0 + quad*4 + q] = p1[q];
          r2s4[h][wave>>1][r0 + quad*4 + q] = p2[q];
        }
      }
    }
  }
  bar_nd();
  if (tid < 32*NH){
    const int h = tid >> 5, r = tid & 31;
    s1[(size_t)h*TOK + t0 + r] = r1s4[h][0][r] + r1s4[h][1][r];
    s2[(size_t)h*TOK + t0 + r] = r2s4[h][0][r] + r2s4[h][1][r];
  }
}

// ---------------- fused FEL (6 GEMMs + LN x2) + WH of att block 0 -------------
__global__ __launch_bounds__(256) void fel_kernel(
    const float* __restrict__ x,
    const u16* __restrict__ w1T, const float* __restrict__ b1,
    const u16* __restrict__ w2T, const float* __restrict__ b2,
    const u16* __restrict__ w3T, const float* __restrict__ b3,
    const u16* __restrict__ w4T, const float* __restrict__ b4,
    const u16* __restrict__ w5T, const float* __restrict__ b5,
    const u16* __restrict__ w6T, const float* __restrict__ b6,
    const u16* __restrict__ WTatt, const float* __restrict__ aatt,
    float* __restrict__ hout, u16* __restrict__ WhT,
    float* __restrict__ s1, float* __restrict__ s2)
{
  const int tid = threadIdx.x;
  const int t0 = blockIdx.x * 32;
  __shared__ __align__(16) u16 AwA[32*ASF];
  __shared__ __align__(16) u16 AwB[32*ASF];
  __shared__ __align__(16) u16 Bs[128*LS];
  __shared__ float scrS[4][16], scrQ[4][16];
  __shared__ float r1s4[H][2][32], r2s4[H][2][32];
  const int wave = tid >> 6, lane = tid & 63, quad = lane >> 4, l15 = lane & 15;
  const int r0 = (wave & 1)*16, c0 = (wave >> 1)*64;
  facc acc[4];
  float rres[4][4];

  // ---- S1: t1 = lrelu(x@f1w1+b1)  (K=32) -> AwB
  { const int row = tid >> 3, ko = tid & 7;
    float4 a0 = *(const float4*)(x + (size_t)(t0+row)*32 + ko*4);
    uint2 u = { pk2(a0.x,a0.y), pk2(a0.z,a0.w) };
    *(uint2*)&AwA[row*ASF + ko*4] = u;
    stageB32(w1T, 32, 0, Bs, tid);
  }
  bar_nd();
  #pragma unroll
  for (int g = 0; g < 4; ++g) acc[g] = (facc){0.f,0.f,0.f,0.f};
  mfma32s(AwA, ASF, Bs, acc, r0, c0, quad, l15);
  #pragma unroll
  for (int g = 0; g < 4; ++g){
    const int c = c0 + g*16 + l15;
    const float bv = b1[c];
    #pragma unroll
    for (int q = 0; q < 4; ++q)
      AwB[(r0 + quad*4 + q)*ASF + c] = f2bf(lrelu(acc[g][q] + bv));
  }

  // ---- S2: res = lrelu(t1@f1w2+b2) (K=128) -> AwA + rres
  #pragma unroll
  for (int g = 0; g < 4; ++g) acc[g] = (facc){0.f,0.f,0.f,0.f};
  gemmAs<2>(AwB, ASF, w2T, 128, Bs, acc, tid, r0, c0, quad, l15);
  #pragma unroll
  for (int g = 0; g < 4; ++g){
    const int c = c0 + g*16 + l15;
    const float bv = b2[c];
    #pragma unroll
    for (int q = 0; q < 4; ++q){
      float xv = lrelu(acc[g][q] + bv);
      AwA[(r0 + quad*4 + q)*ASF + c] = f2bf(xv);
      rres[g][q] = xv;
    }
  }

  // ---- S3: t3 = lrelu(res@f2w1+b3) (K=128, out 256) -> AwB
  #pragma unroll
  for (int ch = 0; ch < 2; ++ch){
    #pragma unroll
    for (int g = 0; g < 4; ++g) acc[g] = (facc){0.f,0.f,0.f,0.f};
    gemmAs<2>(AwA, ASF, w3T + (size_t)ch*128*128, 128, Bs, acc, tid, r0, c0, quad, l15);
    #pragma unroll
    for (int g = 0; g < 4; ++g){
      const int c = c0 + g*16 + l15;
      const float bv = b3[ch*128 + c];
      #pragma unroll
      for (int q = 0; q < 4; ++q)
        AwB[(r0 + quad*4 + q)*ASF + ch*128 + c] = f2bf(lrelu(acc[g][q] + bv));
    }
  }

  // ---- S4: x1 = LN(lrelu(t3@f2w2+b4) + res) (K=256) -> AwA + rres
  #pragma unroll
  for (int g = 0; g < 4; ++g) acc[g] = (facc){0.f,0.f,0.f,0.f};
  gemmAs<4>(AwB, ASF, w4T, 256, Bs, acc, tid, r0, c0, quad, l15);
  {
    float v[4][4], s[4] = {0,0,0,0}, sq[4] = {0,0,0,0};
    #pragma unroll
    for (int g = 0; g < 4; ++g){
      const int c = c0 + g*16 + l15;
      const float bv = b4[c];
      #pragma unroll
      for (int q = 0; q < 4; ++q){
        float xv = lrelu(acc[g][q] + bv) + rres[g][q];
        v[g][q] = xv; s[q] += xv; sq[q] += xv*xv;
      }
    }
    #pragma unroll
    for (int m = 1; m < 16; m <<= 1){
      #pragma unroll
      for (int q = 0; q < 4; ++q){ s[q] += __shfl_xor(s[q], m, 64); sq[q] += __shfl_xor(sq[q], m, 64); }
    }
    if (l15 == 0){
      #pragma unroll
      for (int q = 0; q < 4; ++q){ scrS[wave][quad*4+q] = s[q]; scrQ[wave][quad*4+q] = sq[q]; }
    }
    bar_nd();
    #pragma unroll
    for (int q = 0; q < 4; ++q){
      const int r = r0 + quad*4 + q;
      const float fs = s[q] + scrS[wave^2][quad*4+q];
      const float fq = sq[q] + scrQ[wave^2][quad*4+q];
      const float mean = fs*(1.f/D);
      const float rstd = rsqrtf(fq*(1.f/D) - mean*mean + 1e-5f);
      #pragma unroll
      for (int g = 0; g < 4; ++g){
        const int c = c0 + g*16 + l15;
        float xv = (v[g][q] - mean)*rstd;
        AwA[r*ASF + c] = f2bf(xv);
        rres[g][q] = xv;
      }
    }
  }

  // ---- S5: t5 = lrelu(x1@f3w1+b5) (K=128, out 256) -> AwB
  #pragma unroll
  for (int ch = 0; ch < 2; ++ch){
    #pragma unroll
    for (int g = 0; g < 4; ++g) acc[g] = (facc){0.f,0.f,0.f,0.f};
    gemmAs<2>(AwA, ASF, w5T + (size_t)ch*128*128, 128, Bs, acc, tid, r0, c0, quad, l15);
    #pragma unroll
    for (int g = 0; g < 4; ++g){
      const int c = c0 + g*16 + l15;
      const float bv = b5[ch*128 + c];
      #pragma unroll
      for (int q = 0; q < 4; ++q)
        AwB[(r0 + quad*4 + q)*ASF + ch*128 + c] = f2bf(lrelu(acc[g][q] + bv));
    }
  }

  // ---- S6: out = LN(t5@f3w2+b6 + x1) (K=256) -> hout (fp32) + AwA (bf16)
  #pragma unroll
  for (int g = 0; g < 4; ++g) acc[g] = (facc){0.f,0.f,0.f,0.f};
  gemmAs<4>(AwB, ASF, w6T, 256, Bs, acc, tid, r0, c0, quad, l15);
  {
    float v[4][4], s[4] = {0,0,0,0}, sq[4] = {0,0,0,0};
    #pragma unroll
    for (int g = 0; g < 4; ++g){
      const int c = c0 + g*16 + l15;
      const float bv = b6[c];
      #pragma unroll
      for (int q = 0; q < 4; ++q){
        float xv = acc[g][q] + bv + rres[g][q];
        v[g][q] = xv; s[q] += xv; sq[q] += xv*xv;
      }
    }
    #pragma unroll
    for (int m = 1; m < 16; m <<= 1){
      #pragma unroll
      for (int q = 0; q < 4; ++q){ s[q] += __shfl_xor(s[q], m, 64); sq[q] += __shfl_xor(sq[q], m, 64); }
    }
    if (l15 == 0){
      #pragma unroll
      for (int q = 0; q < 4; ++q){ scrS[wave][quad*4+q] = s[q]; scrQ[wave][quad*4+q] = sq[q]; }
    }
    bar_nd();
    #pragma unroll
    for (int q = 0; q < 4; ++q){
      const int r = r0 + quad*4 + q;
      const float fs = s[q] + scrS[wave^2][quad*4+q];
      const float fq = sq[q] + scrQ[wave^2][quad*4+q];
      const float mean = fs*(1.f/D);
      const float rstd = rsqrtf(fq*(1.f/D) - mean*mean + 1e-5f);
      #pragma unroll
      for (int g = 0; g < 4; ++g){
        const int c = c0 + g*16 + l15;
        float xv = (v[g][q] - mean)*rstd;
        hout[(size_t)(t0 + r)*128 + c] = xv;
        AwA[r*ASF + c] = f2bf(xv);
      }
    }
  }
  wh_phaseS<H>(AwA, ASF, Bs, WTatt, aatt, t0, WhT, s1, s2, r1s4, r2s4, tid);
}

// ---------------- reshwh (512 thr): resh GEMM col-split + LN + WH head-split --
template<int NH>
__global__ __launch_bounds__(512) void reshwh(
    const u16* __restrict__ A, const u16* __restrict__ BT, const float* __restrict__ bias,
    const float* __restrict__ res, float* __restrict__ hout,
    const u16* __restrict__ WT, const float* __restrict__ aatt,
    u16* __restrict__ WhT, float* __restrict__ s1, float* __restrict__ s2)
{
  const int tid = threadIdx.x;
  const int t0 = blockIdx.x * 32;
  __shared__ __align__(16) u16 AsU[2][32*LS];        // A dbuf; reused as Aw (ASW)
  __shared__ __align__(16) u16 Bsg[2][2][64*LS];     // [group][buf]; wh reuses [128*LS]
  __shared__ float scrS[8][32], scrQ[8][32];
  __shared__ float r1s4[NH][2][32], r2s4[NH][2][32];
  const int g = tid >> 8, gtid = tid & 255;
  const int w8 = tid >> 6, lane = tid & 63, quad = lane >> 4, l15 = lane & 15;
  const int wv = gtid >> 6;            // group-local wave 0..3
  const int c0h = wv*16;               // col within group's 64-col half

  // ---- resh GEMM: out cols g*64 + c0h + l15, K=512, dbuf + 2-deep prefetch ----
  facc acc2[2];
  acc2[0] = (facc){0.f,0.f,0.f,0.f}; acc2[1] = (facc){0.f,0.f,0.f,0.f};
  const int arow = tid >> 4, ako = tid & 15;
  const u16* aptr = A + (size_t)(t0+arow)*512 + ako*4;
  uint2 aC = *(const uint2*)aptr;                 // tile 0 A
  BPre2 bC = preBh(BT, 512, 0, gtid, g*64);       // tile 0 B
  uint2 aP = *(const uint2*)(aptr + 64);          // tile 1 A (in flight)
  BPre2 bP = preBh(BT, 512, 64, gtid, g*64);      // tile 1 B (in flight)
  *(uint2*)&AsU[0][arow*LS + ako*4] = aC;
  landBh(bC, Bsg[g][0], gtid);
  bar_nd();
  #pragma unroll
  for (int k = 0; k < 7; ++k){
    const int cur = k & 1, nxt = cur ^ 1;
    uint2 a2 = aP; BPre2 b2 = bP;
    if (k + 2 < 8){                               // issue tile k+2 (2 ahead)
      a2 = *(const uint2*)(aptr + (k+2)*64);
      b2 = preBh(BT, 512, (k+2)*64, gtid, g*64);
    }
    mfma64h(AsU[cur], Bsg[g][cur], acc2, c0h, quad, l15);
    *(uint2*)&AsU[nxt][arow*LS + ako*4] = aP;     // land tile k+1
    landBh(bP, Bsg[g][nxt], gtid);
    aP = a2; bP = b2;
    bar_nd();
  }
  mfma64h(AsU[1], Bsg[g][1], acc2, c0h, quad, l15);

  // ---- bias + residual + LN (8-wave cross reduce) ----
  const int c = g*64 + c0h + l15;
  const float bv = bias[c];
  float v[2][4], s[2][4], sq[2][4];
  #pragma unroll
  for (int rg = 0; rg < 2; ++rg){
    #pragma unroll
    for (int q = 0; q < 4; ++q){
      const int rq = t0 + rg*16 + quad*4 + q;
      float xv = acc2[rg][q] + bv + res[(size_t)rq*128 + c];
      v[rg][q] = xv; s[rg][q] = xv; sq[rg][q] = xv*xv;
    }
  }
  #pragma unroll
  for (int m = 1; m < 16; m <<= 1){
    #pragma unroll
    for (int rg = 0; rg < 2; ++rg)
      #pragma unroll
      for (int q = 0; q < 4; ++q){ s[rg][q] += __shfl_xor(s[rg][q], m, 64); sq[rg][q] += __shfl_xor(sq[rg][q], m, 64); }
  }
  if (l15 == 0){
    #pragma unroll
    for (int rg = 0; rg < 2; ++rg)
      #pragma unroll
      for (int q = 0; q < 4; ++q){
        scrS[w8][rg*16 + quad*4 + q] = s[rg][q];
        scrQ[w8][rg*16 + quad*4 + q] = sq[rg][q];
      }
  }
  bar_nd();           // scr visible; all resh MFMA reads of AsU/Bsg done
  u16* Aw = &AsU[0][0];                // stride ASW (32x136 fits 2x32x72)
  #pragma unroll
  for (int rg = 0; rg < 2; ++rg){
    #pragma unroll
    for (int q = 0; q < 4; ++q){
      const int row = rg*16 + quad*4 + q;
      float fs = 0.f, fq = 0.f;
      #pragma unroll
      for (int w = 0; w < 8; ++w){ fs += scrS[w][row]; fq += scrQ[w][row]; }
      const float mean = fs*(1.f/D);
      const float rstd = rsqrtf(fq*(1.f/D) - mean*mean + 1e-5f);
      float xv = (v[rg][q] - mean)*rstd;
      hout[(size_t)(t0+row)*128 + c] = xv;
      Aw[row*ASW + c] = f2bf(xv);
    }
  }
  bar_nd();           // Aw fully written

  // ---- WH phase: group g -> heads {2g,2g+1} (NH=4) or head 0 (NH=1) ----
  const int NHg = (NH == 4) ? 2 : 1;
  const int hbase = (NH == 4) ? g*2 : 0;
  const bool st = (NH == 4) || (g == 0);
  u16* BsW = &Bsg[g][0][0];            // contiguous [128*LS]
  const int r0w = (wv & 1)*16, c0w = (wv >> 1)*64;
  const int b = t0 >> 9, j0 = t0 & (N-1);
  facc acc[4];
  BPre p = preB64(WT + (size_t)hbase*D*D, D, 0, gtid);
  #pragma unroll
  for (int t = 0; t < 2*NHg; ++t){
    if ((t & 1) == 0){
      #pragma unroll
      for (int gg = 0; gg < 4; ++gg) acc[gg] = (facc){0.f,0.f,0.f,0.f};
    }
    bar_nd();                          // BsW writable
    landB64(p, BsW, gtid);
    if (t + 1 < 2*NHg){
      const int hn = hbase + ((t+1) >> 1);
      p = preB64(WT + (size_t)hn*D*D, D, ((t+1)&1)*64, gtid);
    }
    bar_nd();
    mfma64s(Aw + (t&1)*64, ASW, BsW, acc, r0w, c0w, quad, l15);
    if (t & 1){
      const int h = hbase + (t >> 1);
      const float* ah = aatt + (size_t)h*2*D;
      const size_t obase = (size_t)(h*8 + b)*128;
      float p1[4] = {0,0,0,0}, p2[4] = {0,0,0,0};
      #pragma unroll
      for (int gg = 0; gg < 4; ++gg){
        const int cc = c0w + gg*16 + l15;
        const float a1v = ah[cc], a2v = ah[D + cc];
        if (st){
          ushort4 wvv;
          wvv.x = f2bf(acc[gg][0]); wvv.y = f2bf(acc[gg][1]);
          wvv.z = f2bf(acc[gg][2]); wvv.w = f2bf(acc[gg][3]);
          *(ushort4*)&WhT[(obase + cc)*N + j0 + r0w + quad*4] = wvv;
        }
        #pragma unroll
        for (int q = 0; q < 4; ++q){
          p1[q] = fmaf(acc[gg][q], a1v, p1[q]);
          p2[q] = fmaf(acc[gg][q], a2v, p2[q]);
        }
      }
      #pragma unroll
      for (int m = 1; m < 16; m <<= 1){
        #pragma unroll
        for (int q = 0; q < 4; ++q){ p1[q] += __shfl_xor(p1[q], m, 64); p2[q] += __shfl_xor(p2[q], m, 64); }
      }
      if (st && l15 == 0){
        #pragma unroll
        for (int q = 0; q < 4; ++q){
          r1s4[h][wv>>1][r0w + quad*4 + q] = p1[q];
          r2s4[h][wv>>1][r0w + quad*4 + q] = p2[q];
        }
      }
    }
  }
  bar_nd();
  if (tid < 32*NH){
    const int h = tid >> 5, r = tid & 31;
    s1[(size_t)h*TOK + t0 + r] = r1s4[h][0][r] + r1s4[h][1][r];
    s2[(size_t)h*TOK + t0 + r] = r2s4[h][0][r] + r2s4[h][1][r];
  }
}

// ---- score helper: 4 cols of one row, bitmask from LDS -----------------------
__device__ __forceinline__ float score4(const float* s2s, const unsigned char* mrow,
                                        float s1lr, int k0, int ls, u16* asp){
  float4 sa = *(const float4*)&s2s[k0 + ls*4];
  const u32 mm = (u32)(mrow[(k0 >> 3) + (ls >> 1)]) >> ((ls & 1)*4);
  float ss[4] = {sa.x,sa.y,sa.z,sa.w};
  float v[4]; float p = 0.f;
  #pragma unroll
  for (int i = 0; i < 4; ++i){
    float e = lrelu(s1lr * ss[i]);
    float ex = ((mm >> i) & 1u) ? __expf(e) : 0.f;
    v[i] = ex; p += ex;
  }
  uint2 u = { pk2(v[0],v[1]), pk2(v[2],v[3]) };
  *(uint2*)asp = u;
  return p;
}
// 8-col variant for pvout (256 thr)
__device__ __forceinline__ float score8(const float* s2s, const unsigned char* mrow,
                                        float s1lr, int k0, int lq, u16* asp){
  float4 sa = *(const float4*)&s2s[k0 + lq*8];
  float4 sb = *(const float4*)&s2s[k0 + lq*8 + 4];
  const u32 mm = mrow[(k0 >> 3) + lq];
  float ss[8] = {sa.x,sa.y,sa.z,sa.w,sb.x,sb.y,sb.z,sb.w};
  float v[8]; float p = 0.f;
  #pragma unroll
  for (int i = 0; i < 8; ++i){
    float e = lrelu(s1lr * ss[i]);
    float ex = ((mm >> i) & 1u) ? __expf(e) : 0.f;
    v[i] = ex; p += ex;
  }
  uint4 u = { pk2(v[0],v[1]), pk2(v[2],v[3]), pk2(v[4],v[5]), pk2(v[6],v[7]) };
  *(uint4*)asp = u;
  return p;
}

// ---------------- attention pv (512 thr, col-split groups, elu, bf16 out) -----
// 2-deep B prefetch + nodrain barriers (loads persist across barriers).
__global__ __launch_bounds__(512) void pv32(
    const float* __restrict__ s1, const float* __restrict__ s2,
    const u32* __restrict__ mbits, const u16* __restrict__ WhT,
    u16* __restrict__ out_)
{
  const int tid = threadIdx.x;
  const int h  = blockIdx.x >> 7;
  const int t0 = (blockIdx.x & 127) * 32;
  const int b = t0 >> 9, i0 = t0 & (N-1);
  __shared__ float s2s[N];
  __shared__ float s1s[32], sums[32];
  __shared__ u32 mbs[32*16];
  __shared__ __align__(16) u16 As[2][32*LS];
  __shared__ __align__(16) u16 Bs[2][2][64*LS];     // [group][buf]

  const int g = tid >> 8, gtid = tid & 255;
  const int lane = tid & 63, quad = lane >> 4, l15 = lane & 15;
  const int wv = gtid >> 6;
  const int c0h = wv*16;

  s2s[tid] = s2[(size_t)h*TOK + b*N + tid];
  if (tid < 32) s1s[tid] = s1[(size_t)h*TOK + t0 + tid];
  mbs[tid] = mbits[((size_t)b*N + i0 + (tid >> 4))*16 + (tid & 15)];

  const u16* BTn = WhT + (size_t)(h*8 + b)*128*N;
  facc acc2[2];
  acc2[0] = (facc){0.f,0.f,0.f,0.f}; acc2[1] = (facc){0.f,0.f,0.f,0.f};

  const int lr = tid >> 4, ls = tid & 15;
  const unsigned char* mrow = (const unsigned char*)&mbs[lr*16];
  float psum = 0.f;

  // prologue: tiles 0 and 1 in flight
  BPre2 pC = preBh(BTn, N, 0, gtid, g*64);
  BPre2 pP = preBh(BTn, N, 64, gtid, g*64);
  bar_nd();                             // s2s/s1s/mbs visible
  const float s1lr = s1s[lr];
  psum += score4(s2s, mrow, s1lr, 0, ls, &As[0][lr*LS + ls*4]);
  landBh(pC, Bs[g][0], gtid);
  bar_nd();

  #pragma unroll
  for (int k = 0; k < 7; ++k){
    const int cur = k & 1, nxt = cur ^ 1;
    BPre2 p2 = pP;
    if (k + 2 < 8) p2 = preBh(BTn, N, (k+2)*64, gtid, g*64);   // issue 2 ahead
    psum += score4(s2s, mrow, s1lr, (k+1)*64, ls, &As[nxt][lr*LS + ls*4]);
    mfma64h(As[cur], Bs[g][cur], acc2, c0h, quad, l15);
    landBh(pP, Bs[g][nxt], gtid);                              // land tile k+1
    pP = p2;
    bar_nd();
  }
  mfma64h(As[1], Bs[g][1], acc2, c0h, quad, l15);

  #pragma unroll
  for (int m = 1; m < 16; m <<= 1) psum += __shfl_xor(psum, m, 64);
  if (ls == 0) sums[lr] = psum;
  bar_nd();

  #pragma unroll
  for (int rg = 0; rg < 2; ++rg){
    #pragma unroll
    for (int q = 0; q < 4; ++q){
      const int row = rg*16 + quad*4 + q;
      const float sv = sums[row];
      const float inv = sv > 0.f ? 1.f/sv : 0.f;
      float xv = acc2[rg][q] * inv;
      xv = xv > 0.f ? xv : __expf(xv) - 1.f;     // elu
      out_[(size_t)(t0+row)*512 + h*128 + g*64 + c0h + l15] = f2bf(xv);
    }
  }
}

// ---------------- output-GAT pv (1 head, lrelu) + colsum (+ optional WH) ------
template<int DOWH>
__global__ __launch_bounds__(256) void pvout(
    const float* __restrict__ s1in, const float* __restrict__ s2in,
    const u32* __restrict__ mbits, const u16* __restrict__ WhTin,
    float* __restrict__ hF, float* __restrict__ colsum,
    const u16* __restrict__ WT, const float* __restrict__ aatt,
    u16* __restrict__ WhTout, float* __restrict__ s1out, float* __restrict__ s2out)
{
  const int tid = threadIdx.x;
  const int t0 = blockIdx.x * 32;
  const int b = t0 >> 9, i0 = t0 & (N-1);
  __shared__ float s2s[N];
  __shared__ float s1s[32], sums[32];
  __shared__ u32 mbs[32*16];
  __shared__ __align__(16) u16 AsU[2][32*LS];
  __shared__ __align__(16) u16 Bs[2][128*LS];
  __shared__ float r1s4[H][2][32], r2s4[H][2][32];

  s2s[tid]     = s2in[b*N + tid];
  s2s[tid+256] = s2in[b*N + tid + 256];
  if (tid < 32) s1s[tid] = s1in[t0 + tid];
  { const int r = tid >> 3, wd = (tid & 7)*2;
    *(uint2*)&mbs[r*16 + wd] = *(const uint2*)&mbits[((size_t)b*N + i0 + r)*16 + wd];
  }

  const u16* BTn = WhTin + (size_t)b*128*N;
  const int wave = tid >> 6, lane = tid & 63, quad = lane >> 4, l15 = lane & 15;
  const int c0w = wave*32;
  facc acc[2][2];
  #pragma unroll
  for (int rg = 0; rg < 2; ++rg)
    #pragma unroll
    for (int f = 0; f < 2; ++f) acc[rg][f] = (facc){0.f,0.f,0.f,0.f};

  const int lr = tid >> 3, lq = tid & 7;
  const unsigned char* mrow = (const unsigned char*)&mbs[lr*16];
  const int bn = tid >> 1, bpart = tid & 1;
  const u16* bwp = BTn + (size_t)bn*N + bpart*32;
  float psum = 0.f;

  uint4 g0 = *(const uint4*)bwp,      g1 = *(const uint4*)(bwp+8);
  uint4 g2 = *(const uint4*)(bwp+16), g3 = *(const uint4*)(bwp+24);
  bar_nd();
  const float s1lr = s1s[lr];
  psum += score8(s2s, mrow, s1lr, 0, lq, &AsU[0][lr*LS + lq*8]);
  { u16* bp = &Bs[0][bn*LS + bpart*32];
    *(uint4*)bp = g0; *(uint4*)(bp+8) = g1; *(uint4*)(bp+16) = g2; *(uint4*)(bp+24) = g3; }
  bar_nd();

  #pragma unroll
  for (int k = 0; k < 7; ++k){
    const int cur = k & 1, nxt = cur ^ 1;
    const u16* wp = bwp + (k+1)*64;
    uint4 n0 = *(const uint4*)wp,      n1 = *(const uint4*)(wp+8);
    uint4 n2 = *(const uint4*)(wp+16), n3 = *(const uint4*)(wp+24);
    psum += score8(s2s, mrow, s1lr, (k+1)*64, lq, &AsU[nxt][lr*LS + lq*8]);
    mfma64w(AsU[cur], Bs[cur], acc, c0w, quad, l15);
    { u16* bp = &Bs[nxt][bn*LS + bpart*32];
      *(uint4*)bp = n0; *(uint4*)(bp+8) = n1; *(uint4*)(bp+16) = n2; *(uint4*)(bp+24) = n3; }
    bar_nd();
  }
  mfma64w(AsU[1], Bs[1], acc, c0w, quad, l15);

  #pragma unroll
  for (int m = 1; m < 8; m <<= 1) psum += __shfl_xor(psum, m, 64);
  if (lq == 0) sums[lr] = psum;
  bar_nd();

  u16* Aw = &AsU[0][0];      // stride ASW; safe post-barrier
  float pcs[2] = {0.f, 0.f};
  #pragma unroll
  for (int rg = 0; rg < 2; ++rg){
    #pragma unroll
    for (int q = 0; q < 4; ++q){
      const int row = rg*16 + quad*4 + q;
      const float sv = sums[row];
      const float inv = sv > 0.f ? 1.f/sv : 0.f;
      #pragma unroll
      for (int f = 0; f < 2; ++f){
        const int c = c0w + f*16 + l15;
        float xv = lrelu(acc[rg][f][q] * inv);
        if (DOWH){
          hF[(size_t)(t0+row)*128 + c] = xv;
          Aw[row*ASW + c] = f2bf(xv);
        }
        pcs[f] += xv;
      }
    }
  }
  pcs[0] += __shfl_xor(pcs[0], 16, 64); pcs[0] += __shfl_xor(pcs[0], 32, 64);
  pcs[1] += __shfl_xor(pcs[1], 16, 64); pcs[1] += __shfl_xor(pcs[1], 32, 64);
  if (quad == 0){
    atomicAdd(&colsum[b*128 + c0w + l15], pcs[0]);
    atomicAdd(&colsum[b*128 + c0w + 16 + l15], pcs[1]);
  }
  if (DOWH)
    wh_phaseS<H>(Aw, ASW, &Bs[0][0], WT, aatt, t0, WhTout, s1out, s2out, r1s4, r2s4, tid);
}

// ---------------- projection from pre-reduced column sums ---------------------
__global__ void final_kernel(const float* __restrict__ colsumF, const float* __restrict__ colsumT,
                             const float* __restrict__ pW, const float* __restrict__ pb,
                             float* __restrict__ out)
{
  const int b = blockIdx.x, c = threadIdx.x;
  __shared__ float scr[4];
  float s = ((c < D) ? colsumF[b*D + c] : colsumT[b*D + (c - D)]) * (1.f/N);
  float p = s * pW[c];
  #pragma unroll
  for (int m = 32; m; m >>= 1) p += __shfl_xor(p, m, 64);
  if ((c & 63) == 0) scr[c >> 6] = p;
  __syncthreads();
  if (c == 0) out[b] = scr[0] + scr[1] + scr[2] + scr[3] + pb[0];
}

extern "C" void kernel_launch(void* const* d_in, const int* in_sizes, int n_in,
                              void* d_out, int out_size, void* d_ws, size_t ws_size,
                              hipStream_t stream)
{
  (void)in_sizes; (void)n_in; (void)out_size; (void)ws_size;
  const float* x    = (const float*)d_in[0];
  const int*   adj  = (const int*)d_in[1];
  const float* f1w1 = (const float*)d_in[3];
  const float* f1b1 = (const float*)d_in[4];
  const float* f1w2 = (const float*)d_in[5];
  const float* f1b2 = (const float*)d_in[6];
  const float* f2w1 = (const float*)d_in[7];
  const float* f2b1 = (const float*)d_in[8];
  const float* f2w2 = (const float*)d_in[9];
  const float* f2b2 = (const float*)d_in[10];
  const float* f3w1 = (const float*)d_in[11];
  const float* f3b1 = (const float*)d_in[12];
  const float* f3w2 = (const float*)d_in[13];
  const float* f3b2 = (const float*)d_in[14];
  const float* attW = (const float*)d_in[15];
  const float* attA = (const float*)d_in[16];
  const float* rshW = (const float*)d_in[17];
  const float* rshB = (const float*)d_in[18];
  const float* outW = (const float*)d_in[19];
  const float* outA = (const float*)d_in[20];
  const float* pW   = (const float*)d_in[21];
  const float* pb   = (const float*)d_in[22];

  char* w = (char*)d_ws;
  float* hA  = (float*)w; w += (size_t)TOK*128*4;
  float* hB  = (float*)w; w += (size_t)TOK*128*4;
  float* hF  = (float*)w; w += (size_t)TOK*128*4;
  u16*  hp2  = (u16*)w;  w += (size_t)TOK*512*2;
  u16*  WhT  = (u16*)w;  w += (size_t)H*8*128*N*2;
  u16*  WhT2 = (u16*)w;  w += (size_t)H*8*128*N*2;
  float* s1  = (float*)w; w += (size_t)H*TOK*4;
  float* s2  = (float*)w; w += (size_t)H*TOK*4;
  float* s1b = (float*)w; w += (size_t)H*TOK*4;
  float* s2b = (float*)w; w += (size_t)H*TOK*4;
  u32* mbits = (u32*)w;  w += (size_t)B*N*16*4;
  u32* mtbits= (u32*)w;  w += (size_t)B*N*16*4;
  float* colsumF = (float*)w; w += (size_t)B*128*4;
  float* colsumT = (float*)w; w += (size_t)B*128*4;
  u16* f1w1T = (u16*)w; w += 128*32*2;
  u16* f1w2T = (u16*)w; w += 128*128*2;
  u16* f2w1T = (u16*)w; w += 256*128*2;
  u16* f2w2T = (u16*)w; w += 128*256*2;
  u16* f3w1T = (u16*)w; w += 256*128*2;
  u16* f3w2T = (u16*)w; w += 128*256*2;
  u16* attWT = (u16*)w; w += (size_t)24*128*128*2;
  u16* outWT = (u16*)w; w += (size_t)2*128*128*2;
  u16* rshWT = (u16*)w; w += (size_t)6*128*512*2;

  prep_kernel<<<1461,256,0,stream>>>(adj, mbits, mtbits, colsumF, colsumT,
      f1w1, f1w2, f2w1, f2w2, f3w1, f3w2, attW, outW, rshW,
      f1w1T, f1w2T, f2w1T, f2w2T, f3w1T, f3w2T, attWT, outWT, rshWT);

  // FEL (6 GEMMs + 2 LN) fused + WH(att block 0) -> hA, WhT, s1, s2
  fel_kernel<<<128,256,0,stream>>>(x,
      f1w1T, f1b1, f1w2T, f1b2, f2w1T, f2b1, f2w2T, f2b2, f3w1T, f3b1, f3w2T, f3b2,
      attWT, attA, hA, WhT, s1, s2);

  // forward attention blocks 0..2
  pv32<<<H*128,512,0,stream>>>(s1, s2, mbits, WhT, hp2);
  reshwh<4><<<128,512,0,stream>>>(hp2, rshWT + 0*128*512, rshB + 0*D, hA, hB,
      attWT + (size_t)1*H*D*D, attA + (size_t)1*H*2*D, WhT, s1, s2);
  pv32<<<H*128,512,0,stream>>>(s1, s2, mbits, WhT, hp2);
  reshwh<4><<<128,512,0,stream>>>(hp2, rshWT + (size_t)1*128*512, rshB + 1*D, hB, hA,
      attWT + (size_t)2*H*D*D, attA + (size_t)2*H*2*D, WhT, s1, s2);
  pv32<<<H*128,512,0,stream>>>(s1, s2, mbits, WhT, hp2);
  reshwh<1><<<128,512,0,stream>>>(hp2, rshWT + (size_t)2*128*512, rshB + 2*D, hA, hB,
      outWT, outA, WhT, s1, s2);

  // forward output GAT + colsumF + WH(att block 3) -> hF, WhT2, s1b, s2b
  pvout<1><<<128,256,0,stream>>>(s1, s2, mbits, WhT, hF, colsumF,
      attWT + (size_t)3*H*D*D, attA + (size_t)3*H*2*D, WhT2, s1b, s2b);

  // transposed attention blocks 3..5
  pv32<<<H*128,512,0,stream>>>(s1b, s2b, mtbits, WhT2, hp2);
  reshwh<4><<<128,512,0,stream>>>(hp2, rshWT + (size_t)3*128*512, rshB + 3*D, hF, hA,
      attWT + (size_t)4*H*D*D, attA + (size_t)4*H*2*D, WhT, s1, s2);
  pv32<<<H*128,512,0,stream>>>(s1, s2, mtbits, WhT, hp2);
  reshwh<4><<<128,512,0,stream>>>(hp2, rshWT + (size_t)4*128*512, rshB + 4*D, hA, hB,
      attWT + (size_t)5*H*D*D, attA + (size_t)5*H*2*D, WhT, s1, s2);
  pv32<<<H*128,512,0,stream>>>(s1, s2, mtbits, WhT, hp2);
  reshwh<1><<<128,512,0,stream>>>(hp2, rshWT + (size_t)5*128*512, rshB + 5*D, hB, hA,
      outWT + 128*128, outA + 2*D, WhT, s1, s2);

  // transposed output GAT -> colsumT only
  pvout<0><<<128,256,0,stream>>>(s1, s2, mtbits, WhT, nullptr, colsumT,
      nullptr, nullptr, nullptr, nullptr, nullptr);

  final_kernel<<<B,2*D,0,stream>>>(colsumF, colsumT, pW, pb, (float*)d_out);
}

// Round 9
// 299.671 us; speedup vs baseline: 1.1480x; 1.1480x over previous
//
#include <hip/hip_runtime.h>
#include <math.h>

#define B 8
#define N 512
#define D 128
#define H 4
#define TOK (B*N)   // 4096

typedef __attribute__((ext_vector_type(8))) short bfrag;   // 8 bf16 (4 VGPRs)
typedef __attribute__((ext_vector_type(4))) float facc;    // 4 fp32 acc
typedef unsigned short u16;
typedef unsigned int u32;
typedef unsigned long long u64;

__device__ __forceinline__ float lrelu(float x){ return x > 0.f ? x : 0.01f*x; }
__device__ __forceinline__ u16 f2bf(float f){
  u32 u = __float_as_uint(f);
  u += 0x7fffu + ((u >> 16) & 1u);     // RTNE
  return (u16)(u >> 16);
}
__device__ __forceinline__ u32 pk2(float a, float b){
  return (u32)f2bf(a) | ((u32)f2bf(b) << 16);
}

// LDS row strides (u16): all give bank skew 4/row, 16B-aligned rows
#define LS 72        // B tiles / staged A tiles
#define ASF 264      // fel A tiles (K up to 256)
#define ASW 136      // wh-phase A tiles (K=128)

// ---------------- prep: fully parallel, 1 job per block -----------------------
__global__ void prep_kernel(const int* __restrict__ adj,
    u32* __restrict__ mbits, u32* __restrict__ mtbits,
    float* __restrict__ colsumF, float* __restrict__ colsumT,
    const float* s0, const float* s1_, const float* s2_, const float* s3,
    const float* s4, const float* s5, const float* s6, const float* s7,
    const float* s8,
    u16* d0, u16* d1, u16* d2, u16* d3, u16* d4, u16* d5, u16* d6, u16* d7, u16* d8)
{
  __shared__ int smem[64*65];
  const int tid = threadIdx.x;
  if (blockIdx.x < 512){
    const int tb = blockIdx.x;
    const int b = tb >> 6, i0 = ((tb >> 3) & 7)*64, j0 = (tb & 7)*64;
    #pragma unroll
    for (int i = 0; i < 4; ++i){
      const int r = i*16 + (tid >> 4);
      const int c = (tid & 15)*4;
      int4 v = *(const int4*)&adj[((size_t)b*N + i0 + r)*N + j0 + c];
      smem[r*65 + c]     = v.x; smem[r*65 + c + 1] = v.y;
      smem[r*65 + c + 2] = v.z; smem[r*65 + c + 3] = v.w;
    }
    __syncthreads();
    const int wv = tid >> 6, lane = tid & 63;
    #pragma unroll
    for (int q = 0; q < 16; ++q){
      const int r = wv*16 + q;
      u64 bf_ = __ballot(smem[r*65 + lane] > 0);
      if (lane == 0)
        *(u64*)&mbits[((size_t)b*N + i0 + r)*16 + (j0 >> 5)] = bf_;
      u64 bt_ = __ballot(smem[lane*65 + r] > 0);
      if (lane == 0)
        *(u64*)&mtbits[((size_t)b*N + j0 + r)*16 + (i0 >> 5)] = bt_;
    }
  } else if (blockIdx.x < 1460){
    float* ftile = (float*)smem;        // [32][33]
    const int tx = tid & 31, ty = tid >> 5;
    const float* srcs[9] = {s0,s1_,s2_,s3,s4,s5,s6,s7,s8};
    u16* dsts[9] = {d0,d1,d2,d3,d4,d5,d6,d7,d8};
    const int Ks[9] = {32,128,128,256,128,256,128,128,512};
    const int Ns[9] = {128,128,256,128,256,128,128,128,128};
    const int zs[9] = {1,1,1,1,1,1,24,2,6};
    const int job = (int)blockIdx.x - 512;      // [0,948)
    int m = 0, base = 0;
    for (; m < 9; ++m){
      int cnt = (Ks[m]>>5)*(Ns[m]>>5)*zs[m];
      if (job < base + cnt) break;
      base += cnt;
    }
    const int rem = job - base;
    const int tn = Ns[m] >> 5;
    const int per = (Ks[m] >> 5)*tn;
    const int z = rem / per, t = rem % per;
    const int k0 = (t / tn)*32, n0 = (t % tn)*32;
    const float* src = srcs[m] + (size_t)z*Ks[m]*Ns[m];
    u16* dst = dsts[m] + (size_t)z*Ks[m]*Ns[m];
    for (int r = ty; r < 32; r += 8)
      ftile[r*33 + tx] = src[(size_t)(k0+r)*Ns[m] + n0 + tx];
    __syncthreads();
    for (int r = ty; r < 32; r += 8)
      dst[(size_t)(n0+r)*Ks[m] + k0 + tx] = f2bf(ftile[tx*33 + r]);
  } else {
    float4 z = {0.f,0.f,0.f,0.f};
    *(float4*)&colsumF[tid*4] = z;
    *(float4*)&colsumT[tid*4] = z;
  }
}

// ---- staging helpers ---------------------------------------------------------
struct BPre { uint4 a,b,c,d; };
__device__ __forceinline__ BPre preB64(const u16* __restrict__ BTn, int ldb, int k0, int tid){
  const int n = tid >> 1, part = tid & 1;
  const u16* wp = BTn + (size_t)n*ldb + k0 + part*32;
  BPre r;
  r.a = *(const uint4*)wp;      r.b = *(const uint4*)(wp+8);
  r.c = *(const uint4*)(wp+16); r.d = *(const uint4*)(wp+24);
  return r;
}
__device__ __forceinline__ void landB64(const BPre& p, u16* Bs, int tid){
  const int n = tid >> 1, part = tid & 1;
  u16* bp = &Bs[n*LS + part*32];
  *(uint4*)bp = p.a; *(uint4*)(bp+8) = p.b; *(uint4*)(bp+16) = p.c; *(uint4*)(bp+24) = p.d;
}
__device__ __forceinline__ void stageB32(const u16* __restrict__ BTn, int ldb,
                                         int k0, u16* Bs, int tid){
  const int n = tid >> 1, part = tid & 1;
  const u16* wp = BTn + (size_t)n*ldb + k0 + part*16;
  uint4 w0 = *(const uint4*)wp, w1 = *(const uint4*)(wp+8);
  *(uint4*)&Bs[n*LS + part*16]     = w0;
  *(uint4*)&Bs[n*LS + part*16 + 8] = w1;
}
// 64-row (group-half) B staging: 256 group-threads, 16 u16 each
struct BPre2 { uint4 a,b; };
__device__ __forceinline__ BPre2 preBh(const u16* __restrict__ BTn, int ldb, int k0,
                                       int gtid, int rowoff){
  const u16* wp = BTn + (size_t)(rowoff + (gtid >> 2))*ldb + k0 + (gtid & 3)*16;
  BPre2 r; r.a = *(const uint4*)wp; r.b = *(const uint4*)(wp+8);
  return r;
}
__device__ __forceinline__ void landBh(const BPre2& p, u16* Bs, int gtid){
  u16* bp = &Bs[(gtid >> 2)*LS + (gtid & 3)*16];
  *(uint4*)bp = p.a; *(uint4*)(bp+8) = p.b;
}

// ---- MFMA cores --------------------------------------------------------------
// 4-wave 32x128 mapping (stride-parameterized A)
__device__ __forceinline__ void mfma64s(const u16* As, int sA, const u16* Bs,
                                        facc acc[4], int r0, int c0, int quad, int l15){
  #pragma unroll
  for (int kk = 0; kk < 2; ++kk){
    bfrag af = *(const bfrag*)&As[(r0 + l15)*sA + kk*32 + quad*8];
    #pragma unroll
    for (int g = 0; g < 4; ++g){
      bfrag bf = *(const bfrag*)&Bs[(c0 + g*16 + l15)*LS + kk*32 + quad*8];
      acc[g] = __builtin_amdgcn_mfma_f32_16x16x32_bf16(af, bf, acc[g], 0,0,0);
    }
  }
}
__device__ __forceinline__ void mfma32s(const u16* As, int sA, const u16* Bs,
                                        facc acc[4], int r0, int c0, int quad, int l15){
  bfrag af = *(const bfrag*)&As[(r0 + l15)*sA + quad*8];
  #pragma unroll
  for (int g = 0; g < 4; ++g){
    bfrag bf = *(const bfrag*)&Bs[(c0 + g*16 + l15)*LS + quad*8];
    acc[g] = __builtin_amdgcn_mfma_f32_16x16x32_bf16(af, bf, acc[g], 0,0,0);
  }
}
// wave = 32 rows x 16 cols (col-split groups in pv32/reshwh)
__device__ __forceinline__ void mfma64h(const u16* As, const u16* Bs,
                                        facc acc[2], int c0, int quad, int l15){
  #pragma unroll
  for (int kk = 0; kk < 2; ++kk){
    bfrag af0 = *(const bfrag*)&As[(l15)*LS      + kk*32 + quad*8];
    bfrag af1 = *(const bfrag*)&As[(16 + l15)*LS + kk*32 + quad*8];
    bfrag bf  = *(const bfrag*)&Bs[(c0 + l15)*LS + kk*32 + quad*8];
    acc[0] = __builtin_amdgcn_mfma_f32_16x16x32_bf16(af0, bf, acc[0], 0,0,0);
    acc[1] = __builtin_amdgcn_mfma_f32_16x16x32_bf16(af1, bf, acc[1], 0,0,0);
  }
}
// wave = 32 rows x 32 cols (pvout)
__device__ __forceinline__ void mfma64w(const u16* As, const u16* Bs,
                                        facc acc[2][2], int c0,
                                        int quad, int l15){
  #pragma unroll
  for (int kk = 0; kk < 2; ++kk){
    bfrag af0 = *(const bfrag*)&As[(l15)*LS      + kk*32 + quad*8];
    bfrag af1 = *(const bfrag*)&As[(16 + l15)*LS + kk*32 + quad*8];
    #pragma unroll
    for (int f = 0; f < 2; ++f){
      bfrag bf = *(const bfrag*)&Bs[(c0 + f*16 + l15)*LS + kk*32 + quad*8];
      acc[0][f] = __builtin_amdgcn_mfma_f32_16x16x32_bf16(af0, bf, acc[0][f], 0,0,0);
      acc[1][f] = __builtin_amdgcn_mfma_f32_16x16x32_bf16(af1, bf, acc[1][f], 0,0,0);
    }
  }
}

// ---- single-buffer A-in-LDS GEMM over T 64-wide K tiles (fel) ----------------
template<int T>
__device__ __forceinline__ void gemmAs(const u16* Aw, int sA,
    const u16* __restrict__ BT, int ldb, u16* Bs,
    facc acc[4], int tid, int r0, int c0, int quad, int l15){
  BPre p = preB64(BT, ldb, 0, tid);
  #pragma unroll
  for (int t = 0; t < T; ++t){
    __syncthreads();                       // Bs writable; A writes visible below
    landB64(p, Bs, tid);
    if (t + 1 < T) p = preB64(BT, ldb, (t+1)*64, tid);
    __syncthreads();
    mfma64s(Aw + t*64, sA, Bs, acc, r0, c0, quad, l15);
  }
}

// ---- WH phase (single-buffer, 256-thread version: fel / pvout) ---------------
template<int NH>
__device__ __forceinline__ void wh_phaseS(const u16* Aw, int sA, u16* Bs,
    const u16* __restrict__ WT, const float* __restrict__ aatt,
    int t0, u16* __restrict__ WhT, float* __restrict__ s1, float* __restrict__ s2,
    float (*r1s4)[2][32], float (*r2s4)[2][32], int tid)
{
  const int wave = tid >> 6, lane = tid & 63, quad = lane >> 4, l15 = lane & 15;
  const int r0 = (wave & 1)*16, c0 = (wave >> 1)*64;
  const int b = t0 >> 9, j0 = t0 & (N-1);
  BPre p = preB64(WT, D, 0, tid);
  facc acc[4];
  #pragma unroll
  for (int t = 0; t < 2*NH; ++t){
    if ((t & 1) == 0){
      #pragma unroll
      for (int g = 0; g < 4; ++g) acc[g] = (facc){0.f,0.f,0.f,0.f};
    }
    __syncthreads();                       // Bs writable; Aw visible
    landB64(p, Bs, tid);
    if (t + 1 < 2*NH) p = preB64(WT + (size_t)((t+1)>>1)*D*D, D, ((t+1)&1)*64, tid);
    __syncthreads();
    mfma64s(Aw + (t&1)*64, sA, Bs, acc, r0, c0, quad, l15);
    if (t & 1){
      const int h = t >> 1;
      const float* ah = aatt + (size_t)h*2*D;
      const size_t obase = (size_t)(h*8 + b)*128;
      float p1[4] = {0,0,0,0}, p2[4] = {0,0,0,0};
      #pragma unroll
      for (int g = 0; g < 4; ++g){
        const int c = c0 + g*16 + l15;
        const float a1v = ah[c], a2v = ah[D + c];
        ushort4 wv;
        wv.x = f2bf(acc[g][0]); wv.y = f2bf(acc[g][1]);
        wv.z = f2bf(acc[g][2]); wv.w = f2bf(acc[g][3]);
        *(ushort4*)&WhT[(obase + c)*N + j0 + r0 + quad*4] = wv;
        #pragma unroll
        for (int q = 0; q < 4; ++q){
          p1[q] = fmaf(acc[g][q], a1v, p1[q]);
          p2[q] = fmaf(acc[g][q], a2v, p2[q]);
        }
      }
      #pragma unroll
      for (int m = 1; m < 16; m <<= 1){
        #pragma unroll
        for (int q = 0; q < 4; ++q){ p1[q] += __shfl_xor(p1[q], m, 64); p2[q] += __shfl_xor(p2[q], m, 64); }
      }
      if (l15 == 0){
        #pragma unroll
        for (int q = 0; q < 4; ++q){
          r1s4[h][wave>>1][r0 + quad*4 + q] = p1[q];
          r2s4[h][wave>>1][r0 + quad*4 + q] = p2[q];
        }
      }
    }
  }
  __syncthreads();
  if (tid < 32*NH){
    const int h = tid >> 5, r = tid & 31;
    s1[(size_t)h*TOK + t0 + r] = r1s4[h][0][r] + r1s4[h][1][r];
    s2[(size_t)h*TOK + t0 + r] = r2s4[h][0][r] + r2s4[h][1][r];
  }
}

// ---------------- fused FEL (6 GEMMs + LN x2) + WH of att block 0 -------------
__global__ __launch_bounds__(256) void fel_kernel(
    const float* __restrict__ x,
    const u16* __restrict__ w1T, const float* __restrict__ b1,
    const u16* __restrict__ w2T, const float* __restrict__ b2,
    const u16* __restrict__ w3T, const float* __restrict__ b3,
    const u16* __restrict__ w4T, const float* __restrict__ b4,
    const u16* __restrict__ w5T, const float* __restrict__ b5,
    const u16* __restrict__ w6T, const float* __restrict__ b6,
    const u16* __restrict__ WTatt, const float* __restrict__ aatt,
    float* __restrict__ hout, u16* __restrict__ WhT,
    float* __restrict__ s1, float* __restrict__ s2)
{
  const int tid = threadIdx.x;
  const int t0 = blockIdx.x * 32;
  __shared__ __align__(16) u16 AwA[32*ASF];
  __shared__ __align__(16) u16 AwB[32*ASF];
  __shared__ __align__(16) u16 Bs[128*LS];
  __shared__ float scrS[4][16], scrQ[4][16];
  __shared__ float r1s4[H][2][32], r2s4[H][2][32];
  const int wave = tid >> 6, lane = tid & 63, quad = lane >> 4, l15 = lane & 15;
  const int r0 = (wave & 1)*16, c0 = (wave >> 1)*64;
  facc acc[4];
  float rres[4][4];

  // ---- S1: t1 = lrelu(x@f1w1+b1)  (K=32) -> AwB
  { const int row = tid >> 3, ko = tid & 7;
    float4 a0 = *(const float4*)(x + (size_t)(t0+row)*32 + ko*4);
    uint2 u = { pk2(a0.x,a0.y), pk2(a0.z,a0.w) };
    *(uint2*)&AwA[row*ASF + ko*4] = u;
    stageB32(w1T, 32, 0, Bs, tid);
  }
  __syncthreads();
  #pragma unroll
  for (int g = 0; g < 4; ++g) acc[g] = (facc){0.f,0.f,0.f,0.f};
  mfma32s(AwA, ASF, Bs, acc, r0, c0, quad, l15);
  #pragma unroll
  for (int g = 0; g < 4; ++g){
    const int c = c0 + g*16 + l15;
    const float bv = b1[c];
    #pragma unroll
    for (int q = 0; q < 4; ++q)
      AwB[(r0 + quad*4 + q)*ASF + c] = f2bf(lrelu(acc[g][q] + bv));
  }

  // ---- S2: res = lrelu(t1@f1w2+b2) (K=128) -> AwA + rres
  #pragma unroll
  for (int g = 0; g < 4; ++g) acc[g] = (facc){0.f,0.f,0.f,0.f};
  gemmAs<2>(AwB, ASF, w2T, 128, Bs, acc, tid, r0, c0, quad, l15);
  #pragma unroll
  for (int g = 0; g < 4; ++g){
    const int c = c0 + g*16 + l15;
    const float bv = b2[c];
    #pragma unroll
    for (int q = 0; q < 4; ++q){
      float xv = lrelu(acc[g][q] + bv);
      AwA[(r0 + quad*4 + q)*ASF + c] = f2bf(xv);
      rres[g][q] = xv;
    }
  }

  // ---- S3: t3 = lrelu(res@f2w1+b3) (K=128, out 256) -> AwB
  #pragma unroll
  for (int ch = 0; ch < 2; ++ch){
    #pragma unroll
    for (int g = 0; g < 4; ++g) acc[g] = (facc){0.f,0.f,0.f,0.f};
    gemmAs<2>(AwA, ASF, w3T + (size_t)ch*128*128, 128, Bs, acc, tid, r0, c0, quad, l15);
    #pragma unroll
    for (int g = 0; g < 4; ++g){
      const int c = c0 + g*16 + l15;
      const float bv = b3[ch*128 + c];
      #pragma unroll
      for (int q = 0; q < 4; ++q)
        AwB[(r0 + quad*4 + q)*ASF + ch*128 + c] = f2bf(lrelu(acc[g][q] + bv));
    }
  }

  // ---- S4: x1 = LN(lrelu(t3@f2w2+b4) + res) (K=256) -> AwA + rres
  #pragma unroll
  for (int g = 0; g < 4; ++g) acc[g] = (facc){0.f,0.f,0.f,0.f};
  gemmAs<4>(AwB, ASF, w4T, 256, Bs, acc, tid, r0, c0, quad, l15);
  {
    float v[4][4], s[4] = {0,0,0,0}, sq[4] = {0,0,0,0};
    #pragma unroll
    for (int g = 0; g < 4; ++g){
      const int c = c0 + g*16 + l15;
      const float bv = b4[c];
      #pragma unroll
      for (int q = 0; q < 4; ++q){
        float xv = lrelu(acc[g][q] + bv) + rres[g][q];
        v[g][q] = xv; s[q] += xv; sq[q] += xv*xv;
      }
    }
    #pragma unroll
    for (int m = 1; m < 16; m <<= 1){
      #pragma unroll
      for (int q = 0; q < 4; ++q){ s[q] += __shfl_xor(s[q], m, 64); sq[q] += __shfl_xor(sq[q], m, 64); }
    }
    if (l15 == 0){
      #pragma unroll
      for (int q = 0; q < 4; ++q){ scrS[wave][quad*4+q] = s[q]; scrQ[wave][quad*4+q] = sq[q]; }
    }
    __syncthreads();
    #pragma unroll
    for (int q = 0; q < 4; ++q){
      const int r = r0 + quad*4 + q;
      const float fs = s[q] + scrS[wave^2][quad*4+q];
      const float fq = sq[q] + scrQ[wave^2][quad*4+q];
      const float mean = fs*(1.f/D);
      const float rstd = rsqrtf(fq*(1.f/D) - mean*mean + 1e-5f);
      #pragma unroll
      for (int g = 0; g < 4; ++g){
        const int c = c0 + g*16 + l15;
        float xv = (v[g][q] - mean)*rstd;
        AwA[r*ASF + c] = f2bf(xv);
        rres[g][q] = xv;
      }
    }
  }

  // ---- S5: t5 = lrelu(x1@f3w1+b5) (K=128, out 256) -> AwB
  #pragma unroll
  for (int ch = 0; ch < 2; ++ch){
    #pragma unroll
    for (int g = 0; g < 4; ++g) acc[g] = (facc){0.f,0.f,0.f,0.f};
    gemmAs<2>(AwA, ASF, w5T + (size_t)ch*128*128, 128, Bs, acc, tid, r0, c0, quad, l15);
    #pragma unroll
    for (int g = 0; g < 4; ++g){
      const int c = c0 + g*16 + l15;
      const float bv = b5[ch*128 + c];
      #pragma unroll
      for (int q = 0; q < 4; ++q)
        AwB[(r0 + quad*4 + q)*ASF + ch*128 + c] = f2bf(lrelu(acc[g][q] + bv));
    }
  }

  // ---- S6: out = LN(t5@f3w2+b6 + x1) (K=256) -> hout (fp32) + AwA (bf16)
  #pragma unroll
  for (int g = 0; g < 4; ++g) acc[g] = (facc){0.f,0.f,0.f,0.f};
  gemmAs<4>(AwB, ASF, w6T, 256, Bs, acc, tid, r0, c0, quad, l15);
  {
    float v[4][4], s[4] = {0,0,0,0}, sq[4] = {0,0,0,0};
    #pragma unroll
    for (int g = 0; g < 4; ++g){
      const int c = c0 + g*16 + l15;
      const float bv = b6[c];
      #pragma unroll
      for (int q = 0; q < 4; ++q){
        float xv = acc[g][q] + bv + rres[g][q];
        v[g][q] = xv; s[q] += xv; sq[q] += xv*xv;
      }
    }
    #pragma unroll
    for (int m = 1; m < 16; m <<= 1){
      #pragma unroll
      for (int q = 0; q < 4; ++q){ s[q] += __shfl_xor(s[q], m, 64); sq[q] += __shfl_xor(sq[q], m, 64); }
    }
    if (l15 == 0){
      #pragma unroll
      for (int q = 0; q < 4; ++q){ scrS[wave][quad*4+q] = s[q]; scrQ[wave][quad*4+q] = sq[q]; }
    }
    __syncthreads();
    #pragma unroll
    for (int q = 0; q < 4; ++q){
      const int r = r0 + quad*4 + q;
      const float fs = s[q] + scrS[wave^2][quad*4+q];
      const float fq = sq[q] + scrQ[wave^2][quad*4+q];
      const float mean = fs*(1.f/D);
      const float rstd = rsqrtf(fq*(1.f/D) - mean*mean + 1e-5f);
      #pragma unroll
      for (int g = 0; g < 4; ++g){
        const int c = c0 + g*16 + l15;
        float xv = (v[g][q] - mean)*rstd;
        hout[(size_t)(t0 + r)*128 + c] = xv;
        AwA[r*ASF + c] = f2bf(xv);
      }
    }
  }
  wh_phaseS<H>(AwA, ASF, Bs, WTatt, aatt, t0, WhT, s1, s2, r1s4, r2s4, tid);
}

// ---------------- reshwh (512 thr): resh GEMM col-split + LN + WH head-split --
// 2-deep global prefetch: tile k+2 issued at iter k; tile k+1 lands with a full
// iteration of score/MFMA/barrier latency coverage.
template<int NH>
__global__ __launch_bounds__(512) void reshwh(
    const u16* __restrict__ A, const u16* __restrict__ BT, const float* __restrict__ bias,
    const float* __restrict__ res, float* __restrict__ hout,
    const u16* __restrict__ WT, const float* __restrict__ aatt,
    u16* __restrict__ WhT, float* __restrict__ s1, float* __restrict__ s2)
{
  const int tid = threadIdx.x;
  const int t0 = blockIdx.x * 32;
  __shared__ __align__(16) u16 AsU[2][32*LS];        // A dbuf; reused as Aw (ASW)
  __shared__ __align__(16) u16 Bsg[2][2][64*LS];     // [group][buf]; wh reuses [128*LS]
  __shared__ float scrS[8][32], scrQ[8][32];
  __shared__ float r1s4[NH][2][32], r2s4[NH][2][32];
  const int g = tid >> 8, gtid = tid & 255;
  const int w8 = tid >> 6, lane = tid & 63, quad = lane >> 4, l15 = lane & 15;
  const int wv = gtid >> 6;            // group-local wave 0..3
  const int c0h = wv*16;               // col within group's 64-col half

  // ---- resh GEMM: out cols g*64 + c0h + l15, K=512, dbuf + 2-deep prefetch ----
  facc acc2[2];
  acc2[0] = (facc){0.f,0.f,0.f,0.f}; acc2[1] = (facc){0.f,0.f,0.f,0.f};
  const int arow = tid >> 4, ako = tid & 15;
  const u16* aptr = A + (size_t)(t0+arow)*512 + ako*4;
  uint2 aC = *(const uint2*)aptr;                 // tile 0 A
  BPre2 bC = preBh(BT, 512, 0, gtid, g*64);       // tile 0 B
  uint2 aP = *(const uint2*)(aptr + 64);          // tile 1 A (in flight)
  BPre2 bP = preBh(BT, 512, 64, gtid, g*64);      // tile 1 B (in flight)
  *(uint2*)&AsU[0][arow*LS + ako*4] = aC;
  landBh(bC, Bsg[g][0], gtid);
  __syncthreads();
  #pragma unroll
  for (int k = 0; k < 7; ++k){
    const int cur = k & 1, nxt = cur ^ 1;
    uint2 a2 = aP; BPre2 b2 = bP;
    if (k + 2 < 8){                               // issue tile k+2 (2 ahead)
      a2 = *(const uint2*)(aptr + (k+2)*64);
      b2 = preBh(BT, 512, (k+2)*64, gtid, g*64);
    }
    mfma64h(AsU[cur], Bsg[g][cur], acc2, c0h, quad, l15);
    *(uint2*)&AsU[nxt][arow*LS + ako*4] = aP;     // land tile k+1
    landBh(bP, Bsg[g][nxt], gtid);
    aP = a2; bP = b2;
    __syncthreads();
  }
  mfma64h(AsU[1], Bsg[g][1], acc2, c0h, quad, l15);

  // ---- bias + residual + LN (8-wave cross reduce) ----
  const int c = g*64 + c0h + l15;
  const float bv = bias[c];
  float v[2][4], s[2][4], sq[2][4];
  #pragma unroll
  for (int rg = 0; rg < 2; ++rg){
    #pragma unroll
    for (int q = 0; q < 4; ++q){
      const int rq = t0 + rg*16 + quad*4 + q;
      float xv = acc2[rg][q] + bv + res[(size_t)rq*128 + c];
      v[rg][q] = xv; s[rg][q] = xv; sq[rg][q] = xv*xv;
    }
  }
  #pragma unroll
  for (int m = 1; m < 16; m <<= 1){
    #pragma unroll
    for (int rg = 0; rg < 2; ++rg)
      #pragma unroll
      for (int q = 0; q < 4; ++q){ s[rg][q] += __shfl_xor(s[rg][q], m, 64); sq[rg][q] += __shfl_xor(sq[rg][q], m, 64); }
  }
  if (l15 == 0){
    #pragma unroll
    for (int rg = 0; rg < 2; ++rg)
      #pragma unroll
      for (int q = 0; q < 4; ++q){
        scrS[w8][rg*16 + quad*4 + q] = s[rg][q];
        scrQ[w8][rg*16 + quad*4 + q] = sq[rg][q];
      }
  }
  __syncthreads();    // scr visible; also: all resh MFMA reads of AsU/Bsg done
  u16* Aw = &AsU[0][0];                // stride ASW (32x136 fits 2x32x72)
  #pragma unroll
  for (int rg = 0; rg < 2; ++rg){
    #pragma unroll
    for (int q = 0; q < 4; ++q){
      const int row = rg*16 + quad*4 + q;
      float fs = 0.f, fq = 0.f;
      #pragma unroll
      for (int w = 0; w < 8; ++w){ fs += scrS[w][row]; fq += scrQ[w][row]; }
      const float mean = fs*(1.f/D);
      const float rstd = rsqrtf(fq*(1.f/D) - mean*mean + 1e-5f);
      float xv = (v[rg][q] - mean)*rstd;
      hout[(size_t)(t0+row)*128 + c] = xv;
      Aw[row*ASW + c] = f2bf(xv);
    }
  }
  __syncthreads();    // Aw fully written

  // ---- WH phase: group g -> heads {2g,2g+1} (NH=4) or head 0 (NH=1) ----
  const int NHg = (NH == 4) ? 2 : 1;
  const int hbase = (NH == 4) ? g*2 : 0;
  const bool st = (NH == 4) || (g == 0);
  u16* BsW = &Bsg[g][0][0];            // contiguous [128*LS]
  const int r0w = (wv & 1)*16, c0w = (wv >> 1)*64;
  const int b = t0 >> 9, j0 = t0 & (N-1);
  facc acc[4];
  BPre p = preB64(WT + (size_t)hbase*D*D, D, 0, gtid);
  #pragma unroll
  for (int t = 0; t < 2*NHg; ++t){
    if ((t & 1) == 0){
      #pragma unroll
      for (int gg = 0; gg < 4; ++gg) acc[gg] = (facc){0.f,0.f,0.f,0.f};
    }
    __syncthreads();                   // BsW writable
    landB64(p, BsW, gtid);
    if (t + 1 < 2*NHg){
      const int hn = hbase + ((t+1) >> 1);
      p = preB64(WT + (size_t)hn*D*D, D, ((t+1)&1)*64, gtid);
    }
    __syncthreads();
    mfma64s(Aw + (t&1)*64, ASW, BsW, acc, r0w, c0w, quad, l15);
    if (t & 1){
      const int h = hbase + (t >> 1);
      const float* ah = aatt + (size_t)h*2*D;
      const size_t obase = (size_t)(h*8 + b)*128;
      float p1[4] = {0,0,0,0}, p2[4] = {0,0,0,0};
      #pragma unroll
      for (int gg = 0; gg < 4; ++gg){
        const int cc = c0w + gg*16 + l15;
        const float a1v = ah[cc], a2v = ah[D + cc];
        if (st){
          ushort4 wvv;
          wvv.x = f2bf(acc[gg][0]); wvv.y = f2bf(acc[gg][1]);
          wvv.z = f2bf(acc[gg][2]); wvv.w = f2bf(acc[gg][3]);
          *(ushort4*)&WhT[(obase + cc)*N + j0 + r0w + quad*4] = wvv;
        }
        #pragma unroll
        for (int q = 0; q < 4; ++q){
          p1[q] = fmaf(acc[gg][q], a1v, p1[q]);
          p2[q] = fmaf(acc[gg][q], a2v, p2[q]);
        }
      }
      #pragma unroll
      for (int m = 1; m < 16; m <<= 1){
        #pragma unroll
        for (int q = 0; q < 4; ++q){ p1[q] += __shfl_xor(p1[q], m, 64); p2[q] += __shfl_xor(p2[q], m, 64); }
      }
      if (st && l15 == 0){
        #pragma unroll
        for (int q = 0; q < 4; ++q){
          r1s4[h][wv>>1][r0w + quad*4 + q] = p1[q];
          r2s4[h][wv>>1][r0w + quad*4 + q] = p2[q];
        }
      }
    }
  }
  __syncthreads();
  if (tid < 32*NH){
    const int h = tid >> 5, r = tid & 31;
    s1[(size_t)h*TOK + t0 + r] = r1s4[h][0][r] + r1s4[h][1][r];
    s2[(size_t)h*TOK + t0 + r] = r2s4[h][0][r] + r2s4[h][1][r];
  }
}

// ---- score helper: 4 cols of one row, bitmask from LDS -----------------------
__device__ __forceinline__ float score4(const float* s2s, const unsigned char* mrow,
                                        float s1lr, int k0, int ls, u16* asp){
  float4 sa = *(const float4*)&s2s[k0 + ls*4];
  const u32 mm = (u32)(mrow[(k0 >> 3) + (ls >> 1)]) >> ((ls & 1)*4);
  float ss[4] = {sa.x,sa.y,sa.z,sa.w};
  float v[4]; float p = 0.f;
  #pragma unroll
  for (int i = 0; i < 4; ++i){
    float e = lrelu(s1lr * ss[i]);
    float ex = ((mm >> i) & 1u) ? __expf(e) : 0.f;
    v[i] = ex; p += ex;
  }
  uint2 u = { pk2(v[0],v[1]), pk2(v[2],v[3]) };
  *(uint2*)asp = u;
  return p;
}
// 8-col variant for pvout (256 thr)
__device__ __forceinline__ float score8(const float* s2s, const unsigned char* mrow,
                                        float s1lr, int k0, int lq, u16* asp){
  float4 sa = *(const float4*)&s2s[k0 + lq*8];
  float4 sb = *(const float4*)&s2s[k0 + lq*8 + 4];
  const u32 mm = mrow[(k0 >> 3) + lq];
  float ss[8] = {sa.x,sa.y,sa.z,sa.w,sb.x,sb.y,sb.z,sb.w};
  float v[8]; float p = 0.f;
  #pragma unroll
  for (int i = 0; i < 8; ++i){
    float e = lrelu(s1lr * ss[i]);
    float ex = ((mm >> i) & 1u) ? __expf(e) : 0.f;
    v[i] = ex; p += ex;
  }
  uint4 u = { pk2(v[0],v[1]), pk2(v[2],v[3]), pk2(v[4],v[5]), pk2(v[6],v[7]) };
  *(uint4*)asp = u;
  return p;
}

// ---------------- attention pv (512 thr, col-split groups, elu, bf16 out) -----
// 2-deep B prefetch.
__global__ __launch_bounds__(512) void pv32(
    const float* __restrict__ s1, const float* __restrict__ s2,
    const u32* __restrict__ mbits, const u16* __restrict__ WhT,
    u16* __restrict__ out_)
{
  const int tid = threadIdx.x;
  const int h  = blockIdx.x >> 7;
  const int t0 = (blockIdx.x & 127) * 32;
  const int b = t0 >> 9, i0 = t0 & (N-1);
  __shared__ float s2s[N];
  __shared__ float s1s[32], sums[32];
  __shared__ u32 mbs[32*16];
  __shared__ __align__(16) u16 As[2][32*LS];
  __shared__ __align__(16) u16 Bs[2][2][64*LS];     // [group][buf]

  const int g = tid >> 8, gtid = tid & 255;
  const int lane = tid & 63, quad = lane >> 4, l15 = lane & 15;
  const int wv = gtid >> 6;
  const int c0h = wv*16;

  s2s[tid] = s2[(size_t)h*TOK + b*N + tid];
  if (tid < 32) s1s[tid] = s1[(size_t)h*TOK + t0 + tid];
  mbs[tid] = mbits[((size_t)b*N + i0 + (tid >> 4))*16 + (tid & 15)];

  const u16* BTn = WhT + (size_t)(h*8 + b)*128*N;
  facc acc2[2];
  acc2[0] = (facc){0.f,0.f,0.f,0.f}; acc2[1] = (facc){0.f,0.f,0.f,0.f};

  const int lr = tid >> 4, ls = tid & 15;
  const unsigned char* mrow = (const unsigned char*)&mbs[lr*16];
  float psum = 0.f;

  // prologue: tiles 0 and 1 in flight
  BPre2 pC = preBh(BTn, N, 0, gtid, g*64);
  BPre2 pP = preBh(BTn, N, 64, gtid, g*64);
  __syncthreads();                      // s2s/s1s/mbs visible
  const float s1lr = s1s[lr];
  psum += score4(s2s, mrow, s1lr, 0, ls, &As[0][lr*LS + ls*4]);
  landBh(pC, Bs[g][0], gtid);
  __syncthreads();

  #pragma unroll
  for (int k = 0; k < 7; ++k){
    const int cur = k & 1, nxt = cur ^ 1;
    BPre2 p2 = pP;
    if (k + 2 < 8) p2 = preBh(BTn, N, (k+2)*64, gtid, g*64);   // issue 2 ahead
    psum += score4(s2s, mrow, s1lr, (k+1)*64, ls, &As[nxt][lr*LS + ls*4]);
    mfma64h(As[cur], Bs[g][cur], acc2, c0h, quad, l15);
    landBh(pP, Bs[g][nxt], gtid);                              // land tile k+1
    pP = p2;
    __syncthreads();
  }
  mfma64h(As[1], Bs[g][1], acc2, c0h, quad, l15);

  #pragma unroll
  for (int m = 1; m < 16; m <<= 1) psum += __shfl_xor(psum, m, 64);
  if (ls == 0) sums[lr] = psum;
  __syncthreads();

  #pragma unroll
  for (int rg = 0; rg < 2; ++rg){
    #pragma unroll
    for (int q = 0; q < 4; ++q){
      const int row = rg*16 + quad*4 + q;
      const float sv = sums[row];
      const float inv = sv > 0.f ? 1.f/sv : 0.f;
      float xv = acc2[rg][q] * inv;
      xv = xv > 0.f ? xv : __expf(xv) - 1.f;     // elu
      out_[(size_t)(t0+row)*512 + h*128 + g*64 + c0h + l15] = f2bf(xv);
    }
  }
}

// ---------------- output-GAT pv (1 head, lrelu) + colsum (+ optional WH) ------
template<int DOWH>
__global__ __launch_bounds__(256) void pvout(
    const float* __restrict__ s1in, const float* __restrict__ s2in,
    const u32* __restrict__ mbits, const u16* __restrict__ WhTin,
    float* __restrict__ hF, float* __restrict__ colsum,
    const u16* __restrict__ WT, const float* __restrict__ aatt,
    u16* __restrict__ WhTout, float* __restrict__ s1out, float* __restrict__ s2out)
{
  const int tid = threadIdx.x;
  const int t0 = blockIdx.x * 32;
  const int b = t0 >> 9, i0 = t0 & (N-1);
  __shared__ float s2s[N];
  __shared__ float s1s[32], sums[32];
  __shared__ u32 mbs[32*16];
  __shared__ __align__(16) u16 AsU[2][32*LS];
  __shared__ __align__(16) u16 Bs[2][128*LS];
  __shared__ float r1s4[H][2][32], r2s4[H][2][32];

  s2s[tid]     = s2in[b*N + tid];
  s2s[tid+256] = s2in[b*N + tid + 256];
  if (tid < 32) s1s[tid] = s1in[t0 + tid];
  { const int r = tid >> 3, wd = (tid & 7)*2;
    *(uint2*)&mbs[r*16 + wd] = *(const uint2*)&mbits[((size_t)b*N + i0 + r)*16 + wd];
  }

  const u16* BTn = WhTin + (size_t)b*128*N;
  const int wave = tid >> 6, lane = tid & 63, quad = lane >> 4, l15 = lane & 15;
  const int c0w = wave*32;
  facc acc[2][2];
  #pragma unroll
  for (int rg = 0; rg < 2; ++rg)
    #pragma unroll
    for (int f = 0; f < 2; ++f) acc[rg][f] = (facc){0.f,0.f,0.f,0.f};

  const int lr = tid >> 3, lq = tid & 7;
  const unsigned char* mrow = (const unsigned char*)&mbs[lr*16];
  const int bn = tid >> 1, bpart = tid & 1;
  const u16* bwp = BTn + (size_t)bn*N + bpart*32;
  float psum = 0.f;

  uint4 g0 = *(const uint4*)bwp,      g1 = *(const uint4*)(bwp+8);
  uint4 g2 = *(const uint4*)(bwp+16), g3 = *(const uint4*)(bwp+24);
  __syncthreads();
  const float s1lr = s1s[lr];
  psum += score8(s2s, mrow, s1lr, 0, lq, &AsU[0][lr*LS + lq*8]);
  { u16* bp = &Bs[0][bn*LS + bpart*32];
    *(uint4*)bp = g0; *(uint4*)(bp+8) = g1; *(uint4*)(bp+16) = g2; *(uint4*)(bp+24) = g3; }
  __syncthreads();

  #pragma unroll
  for (int k = 0; k < 7; ++k){
    const int cur = k & 1, nxt = cur ^ 1;
    const u16* wp = bwp + (k+1)*64;
    uint4 n0 = *(const uint4*)wp,      n1 = *(const uint4*)(wp+8);
    uint4 n2 = *(const uint4*)(wp+16), n3 = *(const uint4*)(wp+24);
    psum += score8(s2s, mrow, s1lr, (k+1)*64, lq, &AsU[nxt][lr*LS + lq*8]);
    mfma64w(AsU[cur], Bs[cur], acc, c0w, quad, l15);
    { u16* bp = &Bs[nxt][bn*LS + bpart*32];
      *(uint4*)bp = n0; *(uint4*)(bp+8) = n1; *(uint4*)(bp+16) = n2; *(uint4*)(bp+24) = n3; }
    __syncthreads();
  }
  mfma64w(AsU[1], Bs[1], acc, c0w, quad, l15);

  #pragma unroll
  for (int m = 1; m < 8; m <<= 1) psum += __shfl_xor(psum, m, 64);
  if (lq == 0) sums[lr] = psum;
  __syncthreads();

  u16* Aw = &AsU[0][0];      // stride ASW; safe post-barrier
  float pcs[2] = {0.f, 0.f};
  #pragma unroll
  for (int rg = 0; rg < 2; ++rg){
    #pragma unroll
    for (int q = 0; q < 4; ++q){
      const int row = rg*16 + quad*4 + q;
      const float sv = sums[row];
      const float inv = sv > 0.f ? 1.f/sv : 0.f;
      #pragma unroll
      for (int f = 0; f < 2; ++f){
        const int c = c0w + f*16 + l15;
        float xv = lrelu(acc[rg][f][q] * inv);
        if (DOWH){
          hF[(size_t)(t0+row)*128 + c] = xv;
          Aw[row*ASW + c] = f2bf(xv);
        }
        pcs[f] += xv;
      }
    }
  }
  pcs[0] += __shfl_xor(pcs[0], 16, 64); pcs[0] += __shfl_xor(pcs[0], 32, 64);
  pcs[1] += __shfl_xor(pcs[1], 16, 64); pcs[1] += __shfl_xor(pcs[1], 32, 64);
  if (quad == 0){
    atomicAdd(&colsum[b*128 + c0w + l15], pcs[0]);
    atomicAdd(&colsum[b*128 + c0w + 16 + l15], pcs[1]);
  }
  if (DOWH)
    wh_phaseS<H>(Aw, ASW, &Bs[0][0], WT, aatt, t0, WhTout, s1out, s2out, r1s4, r2s4, tid);
}

// ---------------- projection from pre-reduced column sums ---------------------
__global__ void final_kernel(const float* __restrict__ colsumF, const float* __restrict__ colsumT,
                             const float* __restrict__ pW, const float* __restrict__ pb,
                             float* __restrict__ out)
{
  const int b = blockIdx.x, c = threadIdx.x;
  __shared__ float scr[4];
  float s = ((c < D) ? colsumF[b*D + c] : colsumT[b*D + (c - D)]) * (1.f/N);
  float p = s * pW[c];
  #pragma unroll
  for (int m = 32; m; m >>= 1) p += __shfl_xor(p, m, 64);
  if ((c & 63) == 0) scr[c >> 6] = p;
  __syncthreads();
  if (c == 0) out[b] = scr[0] + scr[1] + scr[2] + scr[3] + pb[0];
}

extern "C" void kernel_launch(void* const* d_in, const int* in_sizes, int n_in,
                              void* d_out, int out_size, void* d_ws, size_t ws_size,
                              hipStream_t stream)
{
  (void)in_sizes; (void)n_in; (void)out_size; (void)ws_size;
  const float* x    = (const float*)d_in[0];
  const int*   adj  = (const int*)d_in[1];
  const float* f1w1 = (const float*)d_in[3];
  const float* f1b1 = (const float*)d_in[4];
  const float* f1w2 = (const float*)d_in[5];
  const float* f1b2 = (const float*)d_in[6];
  const float* f2w1 = (const float*)d_in[7];
  const float* f2b1 = (const float*)d_in[8];
  const float* f2w2 = (const float*)d_in[9];
  const float* f2b2 = (const float*)d_in[10];
  const float* f3w1 = (const float*)d_in[11];
  const float* f3b1 = (const float*)d_in[12];
  const float* f3w2 = (const float*)d_in[13];
  const float* f3b2 = (const float*)d_in[14];
  const float* attW = (const float*)d_in[15];
  const float* attA = (const float*)d_in[16];
  const float* rshW = (const float*)d_in[17];
  const float* rshB = (const float*)d_in[18];
  const float* outW = (const float*)d_in[19];
  const float* outA = (const float*)d_in[20];
  const float* pW   = (const float*)d_in[21];
  const float* pb   = (const float*)d_in[22];

  char* w = (char*)d_ws;
  float* hA  = (float*)w; w += (size_t)TOK*128*4;
  float* hB  = (float*)w; w += (size_t)TOK*128*4;
  float* hF  = (float*)w; w += (size_t)TOK*128*4;
  u16*  hp2  = (u16*)w;  w += (size_t)TOK*512*2;
  u16*  WhT  = (u16*)w;  w += (size_t)H*8*128*N*2;
  u16*  WhT2 = (u16*)w;  w += (size_t)H*8*128*N*2;
  float* s1  = (float*)w; w += (size_t)H*TOK*4;
  float* s2  = (float*)w; w += (size_t)H*TOK*4;
  float* s1b = (float*)w; w += (size_t)H*TOK*4;
  float* s2b = (float*)w; w += (size_t)H*TOK*4;
  u32* mbits = (u32*)w;  w += (size_t)B*N*16*4;
  u32* mtbits= (u32*)w;  w += (size_t)B*N*16*4;
  float* colsumF = (float*)w; w += (size_t)B*128*4;
  float* colsumT = (float*)w; w += (size_t)B*128*4;
  u16* f1w1T = (u16*)w; w += 128*32*2;
  u16* f1w2T = (u16*)w; w += 128*128*2;
  u16* f2w1T = (u16*)w; w += 256*128*2;
  u16* f2w2T = (u16*)w; w += 128*256*2;
  u16* f3w1T = (u16*)w; w += 256*128*2;
  u16* f3w2T = (u16*)w; w += 128*256*2;
  u16* attWT = (u16*)w; w += (size_t)24*128*128*2;
  u16* outWT = (u16*)w; w += (size_t)2*128*128*2;
  u16* rshWT = (u16*)w; w += (size_t)6*128*512*2;

  prep_kernel<<<1461,256,0,stream>>>(adj, mbits, mtbits, colsumF, colsumT,
      f1w1, f1w2, f2w1, f2w2, f3w1, f3w2, attW, outW, rshW,
      f1w1T, f1w2T, f2w1T, f2w2T, f3w1T, f3w2T, attWT, outWT, rshWT);

  // FEL (6 GEMMs + 2 LN) fused + WH(att block 0) -> hA, WhT, s1, s2
  fel_kernel<<<128,256,0,stream>>>(x,
      f1w1T, f1b1, f1w2T, f1b2, f2w1T, f2b1, f2w2T, f2b2, f3w1T, f3b1, f3w2T, f3b2,
      attWT, attA, hA, WhT, s1, s2);

  // forward attention blocks 0..2
  pv32<<<H*128,512,0,stream>>>(s1, s2, mbits, WhT, hp2);
  reshwh<4><<<128,512,0,stream>>>(hp2, rshWT + 0*128*512, rshB + 0*D, hA, hB,
      attWT + (size_t)1*H*D*D, attA + (size_t)1*H*2*D, WhT, s1, s2);
  pv32<<<H*128,512,0,stream>>>(s1, s2, mbits, WhT, hp2);
  reshwh<4><<<128,512,0,stream>>>(hp2, rshWT + (size_t)1*128*512, rshB + 1*D, hB, hA,
      attWT + (size_t)2*H*D*D, attA + (size_t)2*H*2*D, WhT, s1, s2);
  pv32<<<H*128,512,0,stream>>>(s1, s2, mbits, WhT, hp2);
  reshwh<1><<<128,512,0,stream>>>(hp2, rshWT + (size_t)2*128*512, rshB + 2*D, hA, hB,
      outWT, outA, WhT, s1, s2);

  // forward output GAT + colsumF + WH(att block 3) -> hF, WhT2, s1b, s2b
  pvout<1><<<128,256,0,stream>>>(s1, s2, mbits, WhT, hF, colsumF,
      attWT + (size_t)3*H*D*D, attA + (size_t)3*H*2*D, WhT2, s1b, s2b);

  // transposed attention blocks 3..5
  pv32<<<H*128,512,0,stream>>>(s1b, s2b, mtbits, WhT2, hp2);
  reshwh<4><<<128,512,0,stream>>>(hp2, rshWT + (size_t)3*128*512, rshB + 3*D, hF, hA,
      attWT + (size_t)4*H*D*D, attA + (size_t)4*H*2*D, WhT, s1, s2);
  pv32<<<H*128,512,0,stream>>>(s1, s2, mtbits, WhT, hp2);
  reshwh<4><<<128,512,0,stream>>>(hp2, rshWT + (size_t)4*128*512, rshB + 4*D, hA, hB,
      attWT + (size_t)5*H*D*D, attA + (size_t)5*H*2*D, WhT, s1, s2);
  pv32<<<H*128,512,0,stream>>>(s1, s2, mtbits, WhT, hp2);
  reshwh<1><<<128,512,0,stream>>>(hp2, rshWT + (size_t)5*128*512, rshB + 5*D, hB, hA,
      outWT + 128*128, outA + 2*D, WhT, s1, s2);

  // transposed output GAT -> colsumT only
  pvout<0><<<128,256,0,stream>>>(s1, s2, mtbits, WhT, nullptr, colsumT,
      nullptr, nullptr, nullptr, nullptr, nullptr);

  final_kernel<<<B,2*D,0,stream>>>(colsumF, colsumT, pW, pb, (float*)d_out);
}